// Round 6
// baseline (246.427 us; speedup 1.0000x reference)
//
#include <hip/hip_runtime.h>
#include <hip/hip_bf16.h>

#define NNODES 100000
#define NEDGES 1600000
#define INC 128
#define HIDC 64
#define BSHIFT 7                      // 128 nodes per bucket
#define NB ((NNODES + 127) / 128)     // 782 buckets
#define TILE 4096                     // edges per fill1 workgroup (16/thread)
#define HSLOTS 4096                   // LDS hash slots in fill2 (16 KB)
#define CAP 4096                      // staging words per bucket (avg load ~2046)
#define CAPE 4096                     // csr words per bucket (rows padded to x8)
#define NBLK_FILL ((NEDGES + TILE - 1) / TILE)   // 391
#define NBLK_LIN ((NNODES + 63) / 64)            // 1563

typedef short bf16x8 __attribute__((ext_vector_type(8)));
typedef float f32x4 __attribute__((ext_vector_type(4)));

__device__ __forceinline__ float bf2f(unsigned short h) {
    return __uint_as_float((unsigned)h << 16);
}
__device__ __forceinline__ unsigned short f2bf(float f) {
    __hip_bfloat16 h = __float2bfloat16(f);
    return *(unsigned short*)&h;
}

// ---- prep kernel: w1 -> transposed bf16 hi/lo split; w44/bias4 fold; sentinel ----
__global__ __launch_bounds__(256) void prep_w_kernel(
        const float* __restrict__ w1, unsigned short* __restrict__ wTh,
        unsigned short* __restrict__ wTl,
        const float* __restrict__ w2_lin, const float* __restrict__ b2,
        const float* __restrict__ wc, float* __restrict__ w44,
        float* __restrict__ bias4, unsigned short* __restrict__ out) {
    int t = threadIdx.x;
    int e = blockIdx.x * 256 + t;            // 0..8191 over wT[64][128]
    int c = e >> 7, k = e & 127;
    float v = w1[k * 64 + c];
    unsigned short hi = f2bf(v);
    wTh[e] = hi;
    wTl[e] = f2bf(v - bf2f(hi));
    if (blockIdx.x == 0) {
        if (t < 16)   // zero sentinel row for padded gathers
            *(ushort4*)(out + (size_t)NNODES * 64 + t * 4) = make_ushort4(0, 0, 0, 0);
        int kk = t >> 2, j = t & 3;
        float a = 0.0f;
#pragma unroll 8
        for (int i = 0; i < 64; i++) {
            float w4 = (j < 2) ? wc[i * 2 + j] : wc[(64 + i) * 2 + (j - 2)];
            a += w2_lin[kk * 64 + i] * w4;
        }
        w44[kk * 4 + j] = a;
        if (kk == 0) {
            float bb4 = 0.0f;
            for (int i = 0; i < 64; i++) {
                float w4 = (j < 2) ? wc[i * 2 + j] : wc[(64 + i) * 2 + (j - 2)];
                bb4 += b2[i] * w4;
            }
            bias4[j] = bb4;
        }
    }
}

// ---- fat kernel: fill1 binning (blocks [0, NBLK_FILL)) + MFMA lin1 GEMM (rest) ----
// GEMM is bf16x3 error-compensated: x = xh+xl, w = wh+wl (bf16 each);
// h = xh*wh + xh*wl + xl*wh  (xl*wl term ~2^-18 rel, dropped).
// LDS-FREE GEMM: the A-tile has zero inter-lane reuse (each (row,k) feeds
// exactly one lane's fragment) -> load x fragments direct global->reg and
// convert in place; B (32 KB of weights) is L1-resident -> direct dwordx4.
// LDS holds only fill1's arrays (22.6 KB) -> 5 blocks/CU (vs 2 at 64 KB).
__global__ __launch_bounds__(256, 5) void fat_kernel(
        const float* __restrict__ x,
        const unsigned short* __restrict__ wTh, const unsigned short* __restrict__ wTl,
        const float* __restrict__ b, unsigned short* __restrict__ out,
        const int* __restrict__ src, const int* __restrict__ dst,
        int* __restrict__ bucket_fill, unsigned int* __restrict__ staging) {
    __shared__ int cnt[NB];
    __shared__ int basepos[NB];
    __shared__ unsigned int svl[TILE];       // 16 KB
    int t = threadIdx.x;
    if (blockIdx.x < NBLK_FILL) {
        // ---------------- fill1 branch ----------------
        for (int i = t; i < NB; i += 256) cnt[i] = 0;
        __syncthreads();
        int tile0 = blockIdx.x * TILE;
        int meta[16];
#pragma unroll
        for (int i = 0; i < 16; i++) {
            int e = tile0 + i * 256 + t;
            meta[i] = -1;
            if (e < NEDGES) {
                int s = src[e], d = dst[e];
                int bkt = d >> BSHIFT;
                int r = atomicAdd(&cnt[bkt], 1);     // < TILE = 4096 (12 bits)
                meta[i] = (bkt << 12) | r;
                svl[i * 256 + t] = ((unsigned)(d & 127) << 17) | (unsigned)s;
            }
        }
        __syncthreads();
        for (int i = t; i < NB; i += 256) {
            int c = cnt[i];
            int g = (c > 0) ? atomicAdd(&bucket_fill[i], c) : 0;
            basepos[i] = (i << 12) + g;              // staging region = [i*CAP, ...)
        }
        __syncthreads();
#pragma unroll
        for (int i = 0; i < 16; i++) {
            if (meta[i] >= 0) {
                int bkt = meta[i] >> 12, r = meta[i] & 4095;
                staging[basepos[bkt] + r] = svl[i * 256 + t];
            }
        }
    } else {
        // ------- LDS-free MFMA GEMM branch: 64 nodes x 64 cols, K=128 -------
        int node0 = (blockIdx.x - NBLK_FILL) * 64;
        int l = t & 63, wv = t >> 6;
        int mr = l & 15, g = l >> 4;
        int arow = wv * 16 + mr;
        int node = node0 + arow;
        bool vr = (node < NNODES);
        const float* xr = x + (size_t)node * INC;
        f32x4 acc[4] = {{0.f, 0.f, 0.f, 0.f}, {0.f, 0.f, 0.f, 0.f},
                        {0.f, 0.f, 0.f, 0.f}, {0.f, 0.f, 0.f, 0.f}};
#pragma unroll
        for (int ks = 0; ks < 4; ks++) {
            int k0 = ks * 32 + g * 8;
            float4 xa = vr ? *(const float4*)(xr + k0)
                           : make_float4(0.f, 0.f, 0.f, 0.f);
            float4 xb = vr ? *(const float4*)(xr + k0 + 4)
                           : make_float4(0.f, 0.f, 0.f, 0.f);
            float xv[8] = {xa.x, xa.y, xa.z, xa.w, xb.x, xb.y, xb.z, xb.w};
            bf16x8 ah, al;
#pragma unroll
            for (int j = 0; j < 8; j++) {
                unsigned short h = f2bf(xv[j]);
                ah[j] = (short)h;
                al[j] = (short)f2bf(xv[j] - bf2f(h));
            }
#pragma unroll
            for (int cb = 0; cb < 4; cb++) {
                int col = cb * 16 + mr;
                bf16x8 bh = *(const bf16x8*)(wTh + (size_t)col * 128 + k0);
                bf16x8 bl = *(const bf16x8*)(wTl + (size_t)col * 128 + k0);
                acc[cb] = __builtin_amdgcn_mfma_f32_16x16x32_bf16(ah, bh, acc[cb], 0, 0, 0);
                acc[cb] = __builtin_amdgcn_mfma_f32_16x16x32_bf16(ah, bl, acc[cb], 0, 0, 0);
                acc[cb] = __builtin_amdgcn_mfma_f32_16x16x32_bf16(al, bh, acc[cb], 0, 0, 0);
            }
        }
#pragma unroll
        for (int cb = 0; cb < 4; cb++) {
            int col = cb * 16 + mr;
            float bb = b[col];
#pragma unroll
            for (int r = 0; r < 4; r++) {
                int n2 = node0 + wv * 16 + g * 4 + r;
                if (n2 < NNODES)
                    out[(size_t)n2 * 64 + col] = f2bf(acc[cb][r] + bb);
            }
        }
    }
}

// fill pass 2: one WG per 128-node bucket, fixed csr region [b*CAPE, ...).
// Rows padded to x8 with sentinel n_nodes (points at the zero row).
// csr_src stores BYTE offsets (s*128) of the 128-B bufA rows.
__global__ __launch_bounds__(256) void fill2_kernel(
        const int* __restrict__ bucket_fill, const unsigned int* __restrict__ staging,
        int* __restrict__ csr_src, int* __restrict__ row_start,
        int* __restrict__ row_pdeg, float* __restrict__ norm, int n_nodes) {
    __shared__ int cnt[128];
    __shared__ int dcount[128];
    __shared__ int off[128];
    __shared__ int pscan[128];
    __shared__ unsigned short rank16[CAP];   // 8 KB
    __shared__ unsigned int ht[HSLOTS];      // 16 KB
    int t = threadIdx.x;
    int b = blockIdx.x;
    int node0 = b << BSHIFT;
    int nn = min(128, n_nodes - node0);
    if (t < 128) { cnt[t] = 0; dcount[t] = 0; }
    {
        uint4* h4 = (uint4*)ht;
        uint4 ff = make_uint4(0xFFFFFFFFu, 0xFFFFFFFFu, 0xFFFFFFFFu, 0xFFFFFFFFu);
        for (int i = t; i < HSLOTS / 4; i += 256) h4[i] = ff;
    }
    __syncthreads();
    int start = b << 12;
    int total = bucket_fill[b];
    // phase A: count + rank + dedup
    for (int li = t; li < total; li += 256) {
        unsigned int w = staging[start + li];
        int s = (int)(w & 0x1FFFFu);
        int dl = (int)(w >> 17);
        int r = atomicAdd(&cnt[dl], 1);
        rank16[li] = (unsigned short)r;
        if (s != node0 + dl) {  // self-loops merge with the I-diagonal
            unsigned int slot = ((w * 2654435761u) >> 13) & (HSLOTS - 1);
            while (true) {
                unsigned int prev = atomicCAS(&ht[slot], 0xFFFFFFFFu, w);
                if (prev == 0xFFFFFFFFu) { atomicAdd(&dcount[dl], 1); break; }
                if (prev == w) break;
                slot = (slot + 1) & (HSLOTS - 1);
            }
        }
    }
    __syncthreads();
    // exclusive prefix of x8-padded counts -> csr offsets within [b*CAPE, ...)
    int cv = 0, pv = 0;
    if (t < 128) {
        cv = cnt[t];
        pv = (cv + 7) & ~7;
        pscan[t] = pv;
    }
    __syncthreads();
    for (int o = 1; o < 128; o <<= 1) {
        int xx = (t >= o && t < 128) ? pscan[t - o] : 0;
        __syncthreads();
        if (t < 128) pscan[t] += xx;
        __syncthreads();
    }
    if (t < 128) off[t] = b * CAPE + pscan[t] - pv;
    __syncthreads();
    if (t < nn) {
        row_start[node0 + t] = off[t];
        row_pdeg[node0 + t] = pv;
        norm[node0 + t] = 1.0f / (1.0f + (float)dcount[t]);
    }
    // sentinel-pad the tail of each row (byte offset of the zero row)
    if (t < 128)
        for (int k = cv; k < pv; k++) csr_src[off[t] + k] = n_nodes << 7;
    // phase B: scatter csr (byte offsets: s*128)
    for (int li = t; li < total; li += 256) {
        unsigned int w = staging[start + li];
        int s = (int)(w & 0x1FFFFu);
        int dl = (int)(w >> 17);
        csr_src[off[dl] + (int)rank16[li]] = s << 7;
    }
}

// Four nodes per wave: lanes 0-31 own nodes {4q, 4q+1}, lanes 32-63 own
// {4q+2, 4q+3}. Two independent edge streams (X=even node, Y=odd node) per
// half, each keeping the proven wd0/wd1 edge-pairing -> MLP=4 dword gathers
// in flight at the same ~4 VALU/edge. Each dword wave-load still fetches
// exactly 2 full 128-B h1 rows. 100000 = 4*25000: grid exact, no guards.
// csr holds pre-shifted byte offsets (1 v_add addressing); tail slots clamp
// to the sentinel zero row (L1-resident). Fused PAN combine + relu + rank-4
// projection -> u; h1 never hits global memory.
__global__ void agg_h_kernel(const unsigned int* __restrict__ lin32,
                             const int* __restrict__ row_start,
                             const int* __restrict__ row_pdeg,
                             const int* __restrict__ csr_src,
                             const float* __restrict__ norm,
                             const float* __restrict__ wpan, const float* __restrict__ w44,
                             const float* __restrict__ bias4, float* __restrict__ u,
                             int n_nodes) {
    int t = threadIdx.x;
    int lane = t & 63;
    int sl = lane & 31;                      // channel dword / edge slot
    int h5 = lane >> 5;                      // half: owns nodes 4q+2*h5 + {0,1}
    int quad = blockIdx.x * 4 + (t >> 6);
    if (blockIdx.x == 0 && t < 4) u[n_nodes * 4 + t] = 0.0f;  // zero row for agg_pq4 pads
    int nX = quad * 4 + h5 * 2;
    int nY = nX + 1;
    int e0X = row_start[nX], pdX = row_pdeg[nX];
    int e0Y = row_start[nY], pdY = row_pdeg[nY];
    int pm = max(pdX, pdY);
    int pmax = max(pm, __shfl_xor(pm, 32));  // wave-uniform chunk bound
    int sentB = n_nodes << 7;                // byte offset of the zero row
    unsigned sl4 = (unsigned)sl * 4;
    const char* base8 = (const char*)lin32;
    float xL0 = 0.f, xH0 = 0.f, xL1 = 0.f, xH1 = 0.f;
    float yL0 = 0.f, yH0 = 0.f, yL1 = 0.f, yH1 = 0.f;
    for (int base = 0; base < pmax; base += 32) {
        int li = base + sl;
        int soX = (li < pdX) ? csr_src[e0X + li] : sentB;
        int soY = (li < pdY) ? csr_src[e0Y + li] : sentB;
        int m = min(32, pmax - base);        // wave-uniform, multiple of 8
#pragma unroll
        for (int i = 0; i < 32; i += 2) {
            if (i < m) {
                int xA0 = __builtin_amdgcn_readlane(soX, i);
                int xB0 = __builtin_amdgcn_readlane(soX, 32 + i);
                int xA1 = __builtin_amdgcn_readlane(soX, i + 1);
                int xB1 = __builtin_amdgcn_readlane(soX, 33 + i);
                int yA0 = __builtin_amdgcn_readlane(soY, i);
                int yB0 = __builtin_amdgcn_readlane(soY, 32 + i);
                int yA1 = __builtin_amdgcn_readlane(soY, i + 1);
                int yB1 = __builtin_amdgcn_readlane(soY, 33 + i);
                int ox0 = h5 ? xB0 : xA0;
                int ox1 = h5 ? xB1 : xA1;
                int oy0 = h5 ? yB0 : yA0;
                int oy1 = h5 ? yB1 : yA1;
                unsigned int wx0 = *(const unsigned int*)(base8 + (unsigned)(ox0 + sl4));
                unsigned int wx1 = *(const unsigned int*)(base8 + (unsigned)(ox1 + sl4));
                unsigned int wy0 = *(const unsigned int*)(base8 + (unsigned)(oy0 + sl4));
                unsigned int wy1 = *(const unsigned int*)(base8 + (unsigned)(oy1 + sl4));
                xL0 += __uint_as_float(wx0 << 16);
                xH0 += __uint_as_float(wx0 & 0xFFFF0000u);
                xL1 += __uint_as_float(wx1 << 16);
                xH1 += __uint_as_float(wx1 & 0xFFFF0000u);
                yL0 += __uint_as_float(wy0 << 16);
                yH0 += __uint_as_float(wy0 & 0xFFFF0000u);
                yL1 += __uint_as_float(wy1 << 16);
                yH1 += __uint_as_float(wy1 & 0xFFFF0000u);
            }
        }
    }
    float aLX = xL0 + xL1, aHX = xH0 + xH1;
    float aLY = yL0 + yL1, aHY = yH0 + yH1;
    // self rows: 32 consecutive dwords per half -> coalesced
    unsigned int wsX = *(const unsigned int*)(base8 + (unsigned)((nX << 7) + sl4));
    unsigned int wsY = *(const unsigned int*)(base8 + (unsigned)((nY << 7) + sl4));
    float nrX = norm[nX], nrY = norm[nY];
    float w0 = wpan[0];
    float w01 = wpan[0] * wpan[1];
    float vLX = fmaxf(nrX * (w0 * __uint_as_float(wsX << 16) + w01 * aLX), 0.0f);
    float vHX = fmaxf(nrX * (w0 * __uint_as_float(wsX & 0xFFFF0000u) + w01 * aHX), 0.0f);
    float vLY = fmaxf(nrY * (w0 * __uint_as_float(wsY << 16) + w01 * aLY), 0.0f);
    float vHY = fmaxf(nrY * (w0 * __uint_as_float(wsY & 0xFFFF0000u) + w01 * aHY), 0.0f);
    int c0 = 2 * sl;
    float4 wv0 = *(const float4*)(w44 + c0 * 4);
    float4 wv1 = *(const float4*)(w44 + (c0 + 1) * 4);
    float pX0 = vLX * wv0.x + vHX * wv1.x;
    float pX1 = vLX * wv0.y + vHX * wv1.y;
    float pX2 = vLX * wv0.z + vHX * wv1.z;
    float pX3 = vLX * wv0.w + vHX * wv1.w;
    float pY0 = vLY * wv0.x + vHY * wv1.x;
    float pY1 = vLY * wv0.y + vHY * wv1.y;
    float pY2 = vLY * wv0.z + vHY * wv1.z;
    float pY3 = vLY * wv0.w + vHY * wv1.w;
    for (int off = 16; off; off >>= 1) {     // reduce within the 32-lane half
        pX0 += __shfl_xor(pX0, off);
        pX1 += __shfl_xor(pX1, off);
        pX2 += __shfl_xor(pX2, off);
        pX3 += __shfl_xor(pX3, off);
        pY0 += __shfl_xor(pY0, off);
        pY1 += __shfl_xor(pY1, off);
        pY2 += __shfl_xor(pY2, off);
        pY3 += __shfl_xor(pY3, off);
    }
    if (sl == 0) {                           // lanes 0/32 write node X
        float4 bb = *(const float4*)bias4;
        *(float4*)(u + nX * 4) =
            make_float4(pX0 + bb.x, pX1 + bb.y, pX2 + bb.z, pX3 + bb.w);
    }
    if (sl == 1) {                           // lanes 1/33 write node Y
        float4 bb = *(const float4*)bias4;
        *(float4*)(u + nY * 4) =
            make_float4(pY0 + bb.x, pY1 + bb.y, pY2 + bb.z, pY3 + bb.w);
    }
}

// Layer-2 aggregate on the rank-4 table (x8-padded rows, branch-free):
// pq[n,j] = norm*(w0*u[n,j] + w01*sum u[src,j]).  csr holds s*128 byte offsets;
// u row start (float index) = s*4 = offset>>5.
__global__ void agg_pq4_kernel(const float* __restrict__ u, const int* __restrict__ row_start,
                               const int* __restrict__ row_pdeg,
                               const int* __restrict__ csr_src,
                               const float* __restrict__ norm,
                               const float* __restrict__ wpan, float* __restrict__ pq,
                               int n_nodes) {
    int t = threadIdx.x;
    int node = blockIdx.x * 64 + (t >> 2);
    int j = t & 3;
    if (node >= n_nodes) return;
    int e0 = row_start[node];
    int pd = row_pdeg[node];
    float acc = 0.0f;
    for (int e = 0; e < pd; e += 8) {
#pragma unroll
        for (int k = 0; k < 8; k++) {
            int so = csr_src[e0 + e + k];
            acc += u[(so >> 5) + j];
        }
    }
    float w0 = wpan[0];
    float w01 = wpan[0] * wpan[1];
    pq[node * 4 + j] = norm[node] * (w0 * u[node * 4 + j] + w01 * acc);
}

__global__ void edge_out_kernel(const int* __restrict__ src, const int* __restrict__ dst,
                                const float* __restrict__ pq, const float* __restrict__ bc,
                                float* __restrict__ out, int n_edges) {
    int e = blockIdx.x * blockDim.x + threadIdx.x;
    if (e >= n_edges) return;
    int r = src[e], c = dst[e];
    float2 p = *(const float2*)(pq + r * 4);
    float2 q = *(const float2*)(pq + c * 4 + 2);
    float2 o = make_float2(p.x + q.x + bc[0], p.y + q.y + bc[1]);
    *(float2*)(out + e * 2) = o;
}

extern "C" void kernel_launch(void* const* d_in, const int* in_sizes, int n_in,
                              void* d_out, int out_size, void* d_ws, size_t ws_size,
                              hipStream_t stream) {
    const float* x      = (const float*)d_in[0];
    const int*   eidx   = (const int*)d_in[1];
    const float* w1_lin = (const float*)d_in[2];
    const float* b1_lin = (const float*)d_in[3];
    const float* w1_pan = (const float*)d_in[4];
    const float* w2_lin = (const float*)d_in[5];
    const float* b2_lin = (const float*)d_in[6];
    const float* w2_pan = (const float*)d_in[7];
    const float* wc     = (const float*)d_in[8];
    const float* bc     = (const float*)d_in[9];
    float* out = (float*)d_out;

    const int* src = eidx;           // edge_index[0]
    const int* dst = eidx + NEDGES;  // edge_index[1]

    // ---- workspace carve-up (all 256B-aligned) ----
    char* ws = (char*)d_ws;
    size_t off = 0;
    auto carve = [&](size_t bytes) {
        char* p = ws + off;
        off = (off + bytes + 255) & ~(size_t)255;
        return p;
    };
    int*   bucket_fill = (int*)carve((size_t)NB * 4);
    int*   row_start = (int*)carve((size_t)NNODES * 4);
    int*   row_pdeg  = (int*)carve((size_t)NNODES * 4);
    unsigned int* staging = (unsigned int*)carve((size_t)NB * CAP * 4);   // 12.8 MB
    int*   csr_src  = (int*)carve(((size_t)NB * CAPE + 256) * 4);         // 12.8 MB + slack
    float* nrm      = (float*)carve((size_t)NNODES * 4);
    unsigned short* bufA = (unsigned short*)carve((size_t)(NNODES + 1) * HIDC * 2);
    float* u        = (float*)carve((size_t)(NNODES + 1) * 4 * 4);
    float* pq       = (float*)carve((size_t)NNODES * 4 * 4);
    float* w44      = (float*)carve((size_t)64 * 4 * 4);
    float* bias4    = (float*)carve((size_t)4 * 4);
    unsigned short* wTh = (unsigned short*)carve((size_t)HIDC * INC * 2); // 16 KB
    unsigned short* wTl = (unsigned short*)carve((size_t)HIDC * INC * 2); // 16 KB
    (void)ws_size; (void)in_sizes; (void)n_in; (void)out_size;

    hipMemsetAsync(bucket_fill, 0, (size_t)NB * 4, stream);

    // prep: wT bf16 hi/lo split + w44/bias4 fold + bufA sentinel row
    prep_w_kernel<<<32, 256, 0, stream>>>(w1_lin, wTh, wTl, w2_lin, b2_lin, wc,
                                          w44, bias4, bufA);

    // fat kernel: edge binning (first 391 blocks) || layer-1 MFMA GEMM (LDS-free)
    fat_kernel<<<NBLK_FILL + NBLK_LIN, 256, 0, stream>>>(
        x, wTh, wTl, b1_lin, bufA, src, dst, bucket_fill, staging);

    // CSR build pass 2: x8-padded rows + row_start/pdeg + dedup + norm + scatter
    fill2_kernel<<<NB, 256, 0, stream>>>(bucket_fill, staging, csr_src, row_start, row_pdeg,
                                         nrm, NNODES);

    // layer 1 aggregate+relu fused with rank-4 projection -> u (4 nodes/wave)
    agg_h_kernel<<<(NNODES / 16), 256, 0, stream>>>(
        (const unsigned int*)bufA, row_start, row_pdeg, csr_src, nrm, w1_pan, w44, bias4,
        u, NNODES);

    // layer 2 aggregate on the rank-4 table
    agg_pq4_kernel<<<(NNODES + 63) / 64, 256, 0, stream>>>(
        u, row_start, row_pdeg, csr_src, nrm, w2_pan, pq, NNODES);

    // edge head: out[e] = p[src[e]] + q[dst[e]] + bc
    edge_out_kernel<<<NEDGES / 256, 256, 0, stream>>>(src, dst, pq, bc, out, NEDGES);
}

// Round 7
// 226.679 us; speedup vs baseline: 1.0871x; 1.0871x over previous
//
#include <hip/hip_runtime.h>
#include <hip/hip_bf16.h>

#define NNODES 100000
#define NEDGES 1600000
#define INC 128
#define HIDC 64
#define BSHIFT 7                      // 128 nodes per bucket
#define NB ((NNODES + 127) / 128)     // 782 buckets
#define TILE 4096                     // edges per fill1 workgroup (16/thread)
#define HSLOTS 4096                   // LDS hash slots in fill2 (16 KB)
#define CAP 4096                      // staging words per bucket (avg load ~2046)
#define CAPE 4096                     // csr words per bucket (rows padded to x8)
#define NBLK_FILL ((NEDGES + TILE - 1) / TILE)   // 391
#define NBLK_LIN ((NNODES + 63) / 64)            // 1563

typedef short bf16x8 __attribute__((ext_vector_type(8)));
typedef float f32x4 __attribute__((ext_vector_type(4)));

__device__ __forceinline__ float bf2f(unsigned short h) {
    return __uint_as_float((unsigned)h << 16);
}
__device__ __forceinline__ unsigned short f2bf(float f) {
    __hip_bfloat16 h = __float2bfloat16(f);
    return *(unsigned short*)&h;
}

// ---- prep kernel: w1 -> transposed bf16 hi/lo split; w44/bias4 fold; sentinel ----
__global__ __launch_bounds__(256) void prep_w_kernel(
        const float* __restrict__ w1, unsigned short* __restrict__ wTh,
        unsigned short* __restrict__ wTl,
        const float* __restrict__ w2_lin, const float* __restrict__ b2,
        const float* __restrict__ wc, float* __restrict__ w44,
        float* __restrict__ bias4, unsigned short* __restrict__ out) {
    int t = threadIdx.x;
    int e = blockIdx.x * 256 + t;            // 0..8191 over wT[64][128]
    int c = e >> 7, k = e & 127;
    float v = w1[k * 64 + c];
    unsigned short hi = f2bf(v);
    wTh[e] = hi;
    wTl[e] = f2bf(v - bf2f(hi));
    if (blockIdx.x == 0) {
        if (t < 16)   // zero sentinel row for padded gathers
            *(ushort4*)(out + (size_t)NNODES * 64 + t * 4) = make_ushort4(0, 0, 0, 0);
        int kk = t >> 2, j = t & 3;
        float a = 0.0f;
#pragma unroll 8
        for (int i = 0; i < 64; i++) {
            float w4 = (j < 2) ? wc[i * 2 + j] : wc[(64 + i) * 2 + (j - 2)];
            a += w2_lin[kk * 64 + i] * w4;
        }
        w44[kk * 4 + j] = a;
        if (kk == 0) {
            float bb4 = 0.0f;
            for (int i = 0; i < 64; i++) {
                float w4 = (j < 2) ? wc[i * 2 + j] : wc[(64 + i) * 2 + (j - 2)];
                bb4 += b2[i] * w4;
            }
            bias4[j] = bb4;
        }
    }
}

// ---- fat kernel: fill1 binning (blocks [0, NBLK_FILL)) + MFMA lin1 GEMM (rest) ----
// GEMM is bf16x3 error-compensated: x = xh+xl, w = wh+wl (bf16 each);
// h = xh*wh + xh*wl + xl*wh  (xl*wl term ~2^-18 rel, dropped).
// HYBRID staging (R5/R6 lessons): A (x rows) has ZERO inter-lane reuse ->
// direct global->reg, 8 independent loads up-front (R6's working half).
// B (32 KB weights) has 4x per-block reuse -> LDS-staged, swizzled, loaded
// cooperatively once + 1 barrier (R5's working half). Avoids both R5's
// useless 32 KB A-tile and R6's 32-per-thread serialized B-load chain
// (VGPR=36 couldn't pipeline it -> 6% VALUBusy).
__global__ __launch_bounds__(256, 5) void fat_kernel(
        const float* __restrict__ x,
        const unsigned short* __restrict__ wTh, const unsigned short* __restrict__ wTl,
        const float* __restrict__ b, unsigned short* __restrict__ out,
        const int* __restrict__ src, const int* __restrict__ dst,
        int* __restrict__ bucket_fill, unsigned int* __restrict__ staging) {
    __shared__ alignas(16) unsigned char smem[32768];   // union: fill1 22.6KB | B 32KB
    int t = threadIdx.x;
    if (blockIdx.x < NBLK_FILL) {
        // ---------------- fill1 branch ----------------
        int* cnt = (int*)smem;
        int* basepos = cnt + NB;
        unsigned int* svl = (unsigned int*)(basepos + NB);   // 4096 words = TILE
        for (int i = t; i < NB; i += 256) cnt[i] = 0;
        __syncthreads();
        int tile0 = blockIdx.x * TILE;
        int meta[16];
#pragma unroll
        for (int i = 0; i < 16; i++) {
            int e = tile0 + i * 256 + t;
            meta[i] = -1;
            if (e < NEDGES) {
                int s = src[e], d = dst[e];
                int bkt = d >> BSHIFT;
                int r = atomicAdd(&cnt[bkt], 1);     // < TILE = 4096 (12 bits)
                meta[i] = (bkt << 12) | r;
                svl[i * 256 + t] = ((unsigned)(d & 127) << 17) | (unsigned)s;
            }
        }
        __syncthreads();
        for (int i = t; i < NB; i += 256) {
            int c = cnt[i];
            int g = (c > 0) ? atomicAdd(&bucket_fill[i], c) : 0;
            basepos[i] = (i << 12) + g;              // staging region = [i*CAP, ...)
        }
        __syncthreads();
#pragma unroll
        for (int i = 0; i < 16; i++) {
            if (meta[i] >= 0) {
                int bkt = meta[i] >> 12, r = meta[i] & 4095;
                staging[basepos[bkt] + r] = svl[i * 256 + t];
            }
        }
    } else {
        // ------- hybrid MFMA GEMM branch: 64 nodes x 64 cols, K=128 -------
        unsigned short* s_bh = (unsigned short*)smem;        // [64][128] swizzled
        unsigned short* s_bl = s_bh + 64 * 128;
        int node0 = (blockIdx.x - NBLK_FILL) * 64;
        int l = t & 63, wv = t >> 6;
        int mr = l & 15, g = l >> 4;
        int arow = wv * 16 + mr;
        int node = node0 + arow;
        bool vr = (node < NNODES);
        const float* xr = x + (size_t)node * INC;
        // issue A loads up-front (8 independent float4s -> in flight together)
        float4 vx[8];
#pragma unroll
        for (int ks = 0; ks < 4; ks++) {
            int k0 = ks * 32 + g * 8;
            vx[2 * ks]     = vr ? *(const float4*)(xr + k0)
                                : make_float4(0.f, 0.f, 0.f, 0.f);
            vx[2 * ks + 1] = vr ? *(const float4*)(xr + k0 + 4)
                                : make_float4(0.f, 0.f, 0.f, 0.f);
        }
        // cooperative B staging: 1024+1024 uint4s, coalesced, swizzled store
#pragma unroll
        for (int i = 0; i < 4; i++) {
            int e = i * 256 + t;                     // ushort8 chunk of wT[64][128]
            uint4 vh = *(const uint4*)(wTh + (size_t)e * 8);
            uint4 vl = *(const uint4*)(wTl + (size_t)e * 8);
            int col = e >> 4, k0 = (e & 15) * 8;
            int ke = k0 ^ ((col & 7) << 3);
            *(uint4*)&s_bh[col * 128 + ke] = vh;
            *(uint4*)&s_bl[col * 128 + ke] = vl;
        }
        __syncthreads();
        f32x4 acc[4] = {{0.f, 0.f, 0.f, 0.f}, {0.f, 0.f, 0.f, 0.f},
                        {0.f, 0.f, 0.f, 0.f}, {0.f, 0.f, 0.f, 0.f}};
#pragma unroll
        for (int ks = 0; ks < 4; ks++) {
            int k0 = ks * 32 + g * 8;
            float xv[8] = {vx[2 * ks].x, vx[2 * ks].y, vx[2 * ks].z, vx[2 * ks].w,
                           vx[2 * ks + 1].x, vx[2 * ks + 1].y,
                           vx[2 * ks + 1].z, vx[2 * ks + 1].w};
            bf16x8 ah, al;
#pragma unroll
            for (int j = 0; j < 8; j++) {
                unsigned short h = f2bf(xv[j]);
                ah[j] = (short)h;
                al[j] = (short)f2bf(xv[j] - bf2f(h));
            }
#pragma unroll
            for (int cb = 0; cb < 4; cb++) {
                int col = cb * 16 + mr;
                int ko = k0 ^ ((col & 7) << 3);
                bf16x8 bh = *(const bf16x8*)&s_bh[col * 128 + ko];
                bf16x8 bl = *(const bf16x8*)&s_bl[col * 128 + ko];
                acc[cb] = __builtin_amdgcn_mfma_f32_16x16x32_bf16(ah, bh, acc[cb], 0, 0, 0);
                acc[cb] = __builtin_amdgcn_mfma_f32_16x16x32_bf16(ah, bl, acc[cb], 0, 0, 0);
                acc[cb] = __builtin_amdgcn_mfma_f32_16x16x32_bf16(al, bh, acc[cb], 0, 0, 0);
            }
        }
#pragma unroll
        for (int cb = 0; cb < 4; cb++) {
            int col = cb * 16 + mr;
            float bb = b[col];
#pragma unroll
            for (int r = 0; r < 4; r++) {
                int n2 = node0 + wv * 16 + g * 4 + r;
                if (n2 < NNODES)
                    out[(size_t)n2 * 64 + col] = f2bf(acc[cb][r] + bb);
            }
        }
    }
}

// fill pass 2: one WG per 128-node bucket, fixed csr region [b*CAPE, ...).
// Rows padded to x8 with sentinel n_nodes (points at the zero row).
// csr_src stores BYTE offsets (s*128) of the 128-B bufA rows.
__global__ __launch_bounds__(256) void fill2_kernel(
        const int* __restrict__ bucket_fill, const unsigned int* __restrict__ staging,
        int* __restrict__ csr_src, int* __restrict__ row_start,
        int* __restrict__ row_pdeg, float* __restrict__ norm, int n_nodes) {
    __shared__ int cnt[128];
    __shared__ int dcount[128];
    __shared__ int off[128];
    __shared__ int pscan[128];
    __shared__ unsigned short rank16[CAP];   // 8 KB
    __shared__ unsigned int ht[HSLOTS];      // 16 KB
    int t = threadIdx.x;
    int b = blockIdx.x;
    int node0 = b << BSHIFT;
    int nn = min(128, n_nodes - node0);
    if (t < 128) { cnt[t] = 0; dcount[t] = 0; }
    {
        uint4* h4 = (uint4*)ht;
        uint4 ff = make_uint4(0xFFFFFFFFu, 0xFFFFFFFFu, 0xFFFFFFFFu, 0xFFFFFFFFu);
        for (int i = t; i < HSLOTS / 4; i += 256) h4[i] = ff;
    }
    __syncthreads();
    int start = b << 12;
    int total = bucket_fill[b];
    // phase A: count + rank + dedup
    for (int li = t; li < total; li += 256) {
        unsigned int w = staging[start + li];
        int s = (int)(w & 0x1FFFFu);
        int dl = (int)(w >> 17);
        int r = atomicAdd(&cnt[dl], 1);
        rank16[li] = (unsigned short)r;
        if (s != node0 + dl) {  // self-loops merge with the I-diagonal
            unsigned int slot = ((w * 2654435761u) >> 13) & (HSLOTS - 1);
            while (true) {
                unsigned int prev = atomicCAS(&ht[slot], 0xFFFFFFFFu, w);
                if (prev == 0xFFFFFFFFu) { atomicAdd(&dcount[dl], 1); break; }
                if (prev == w) break;
                slot = (slot + 1) & (HSLOTS - 1);
            }
        }
    }
    __syncthreads();
    // exclusive prefix of x8-padded counts -> csr offsets within [b*CAPE, ...)
    int cv = 0, pv = 0;
    if (t < 128) {
        cv = cnt[t];
        pv = (cv + 7) & ~7;
        pscan[t] = pv;
    }
    __syncthreads();
    for (int o = 1; o < 128; o <<= 1) {
        int xx = (t >= o && t < 128) ? pscan[t - o] : 0;
        __syncthreads();
        if (t < 128) pscan[t] += xx;
        __syncthreads();
    }
    if (t < 128) off[t] = b * CAPE + pscan[t] - pv;
    __syncthreads();
    if (t < nn) {
        row_start[node0 + t] = off[t];
        row_pdeg[node0 + t] = pv;
        norm[node0 + t] = 1.0f / (1.0f + (float)dcount[t]);
    }
    // sentinel-pad the tail of each row (byte offset of the zero row)
    if (t < 128)
        for (int k = cv; k < pv; k++) csr_src[off[t] + k] = n_nodes << 7;
    // phase B: scatter csr (byte offsets: s*128)
    for (int li = t; li < total; li += 256) {
        unsigned int w = staging[start + li];
        int s = (int)(w & 0x1FFFFu);
        int dl = (int)(w >> 17);
        csr_src[off[dl] + (int)rank16[li]] = s << 7;
    }
}

// Four nodes per wave: lanes 0-31 own nodes {4q, 4q+1}, lanes 32-63 own
// {4q+2, 4q+3}. Two independent edge streams (X=even node, Y=odd node) per
// half, each keeping the proven wd0/wd1 edge-pairing -> MLP=4 dword gathers
// in flight at the same ~4 VALU/edge. Each dword wave-load still fetches
// exactly 2 full 128-B h1 rows. 100000 = 4*25000: grid exact, no guards.
// csr holds pre-shifted byte offsets (1 v_add addressing); tail slots clamp
// to the sentinel zero row (L1-resident). Fused PAN combine + relu + rank-4
// projection -> u; h1 never hits global memory.
__global__ void agg_h_kernel(const unsigned int* __restrict__ lin32,
                             const int* __restrict__ row_start,
                             const int* __restrict__ row_pdeg,
                             const int* __restrict__ csr_src,
                             const float* __restrict__ norm,
                             const float* __restrict__ wpan, const float* __restrict__ w44,
                             const float* __restrict__ bias4, float* __restrict__ u,
                             int n_nodes) {
    int t = threadIdx.x;
    int lane = t & 63;
    int sl = lane & 31;                      // channel dword / edge slot
    int h5 = lane >> 5;                      // half: owns nodes 4q+2*h5 + {0,1}
    int quad = blockIdx.x * 4 + (t >> 6);
    if (blockIdx.x == 0 && t < 4) u[n_nodes * 4 + t] = 0.0f;  // zero row for agg_pq4 pads
    int nX = quad * 4 + h5 * 2;
    int nY = nX + 1;
    int e0X = row_start[nX], pdX = row_pdeg[nX];
    int e0Y = row_start[nY], pdY = row_pdeg[nY];
    int pm = max(pdX, pdY);
    int pmax = max(pm, __shfl_xor(pm, 32));  // wave-uniform chunk bound
    int sentB = n_nodes << 7;                // byte offset of the zero row
    unsigned sl4 = (unsigned)sl * 4;
    const char* base8 = (const char*)lin32;
    float xL0 = 0.f, xH0 = 0.f, xL1 = 0.f, xH1 = 0.f;
    float yL0 = 0.f, yH0 = 0.f, yL1 = 0.f, yH1 = 0.f;
    for (int base = 0; base < pmax; base += 32) {
        int li = base + sl;
        int soX = (li < pdX) ? csr_src[e0X + li] : sentB;
        int soY = (li < pdY) ? csr_src[e0Y + li] : sentB;
        int m = min(32, pmax - base);        // wave-uniform, multiple of 8
#pragma unroll
        for (int i = 0; i < 32; i += 2) {
            if (i < m) {
                int xA0 = __builtin_amdgcn_readlane(soX, i);
                int xB0 = __builtin_amdgcn_readlane(soX, 32 + i);
                int xA1 = __builtin_amdgcn_readlane(soX, i + 1);
                int xB1 = __builtin_amdgcn_readlane(soX, 33 + i);
                int yA0 = __builtin_amdgcn_readlane(soY, i);
                int yB0 = __builtin_amdgcn_readlane(soY, 32 + i);
                int yA1 = __builtin_amdgcn_readlane(soY, i + 1);
                int yB1 = __builtin_amdgcn_readlane(soY, 33 + i);
                int ox0 = h5 ? xB0 : xA0;
                int ox1 = h5 ? xB1 : xA1;
                int oy0 = h5 ? yB0 : yA0;
                int oy1 = h5 ? yB1 : yA1;
                unsigned int wx0 = *(const unsigned int*)(base8 + (unsigned)(ox0 + sl4));
                unsigned int wx1 = *(const unsigned int*)(base8 + (unsigned)(ox1 + sl4));
                unsigned int wy0 = *(const unsigned int*)(base8 + (unsigned)(oy0 + sl4));
                unsigned int wy1 = *(const unsigned int*)(base8 + (unsigned)(oy1 + sl4));
                xL0 += __uint_as_float(wx0 << 16);
                xH0 += __uint_as_float(wx0 & 0xFFFF0000u);
                xL1 += __uint_as_float(wx1 << 16);
                xH1 += __uint_as_float(wx1 & 0xFFFF0000u);
                yL0 += __uint_as_float(wy0 << 16);
                yH0 += __uint_as_float(wy0 & 0xFFFF0000u);
                yL1 += __uint_as_float(wy1 << 16);
                yH1 += __uint_as_float(wy1 & 0xFFFF0000u);
            }
        }
    }
    float aLX = xL0 + xL1, aHX = xH0 + xH1;
    float aLY = yL0 + yL1, aHY = yH0 + yH1;
    // self rows: 32 consecutive dwords per half -> coalesced
    unsigned int wsX = *(const unsigned int*)(base8 + (unsigned)((nX << 7) + sl4));
    unsigned int wsY = *(const unsigned int*)(base8 + (unsigned)((nY << 7) + sl4));
    float nrX = norm[nX], nrY = norm[nY];
    float w0 = wpan[0];
    float w01 = wpan[0] * wpan[1];
    float vLX = fmaxf(nrX * (w0 * __uint_as_float(wsX << 16) + w01 * aLX), 0.0f);
    float vHX = fmaxf(nrX * (w0 * __uint_as_float(wsX & 0xFFFF0000u) + w01 * aHX), 0.0f);
    float vLY = fmaxf(nrY * (w0 * __uint_as_float(wsY << 16) + w01 * aLY), 0.0f);
    float vHY = fmaxf(nrY * (w0 * __uint_as_float(wsY & 0xFFFF0000u) + w01 * aHY), 0.0f);
    int c0 = 2 * sl;
    float4 wv0 = *(const float4*)(w44 + c0 * 4);
    float4 wv1 = *(const float4*)(w44 + (c0 + 1) * 4);
    float pX0 = vLX * wv0.x + vHX * wv1.x;
    float pX1 = vLX * wv0.y + vHX * wv1.y;
    float pX2 = vLX * wv0.z + vHX * wv1.z;
    float pX3 = vLX * wv0.w + vHX * wv1.w;
    float pY0 = vLY * wv0.x + vHY * wv1.x;
    float pY1 = vLY * wv0.y + vHY * wv1.y;
    float pY2 = vLY * wv0.z + vHY * wv1.z;
    float pY3 = vLY * wv0.w + vHY * wv1.w;
    for (int off = 16; off; off >>= 1) {     // reduce within the 32-lane half
        pX0 += __shfl_xor(pX0, off);
        pX1 += __shfl_xor(pX1, off);
        pX2 += __shfl_xor(pX2, off);
        pX3 += __shfl_xor(pX3, off);
        pY0 += __shfl_xor(pY0, off);
        pY1 += __shfl_xor(pY1, off);
        pY2 += __shfl_xor(pY2, off);
        pY3 += __shfl_xor(pY3, off);
    }
    if (sl == 0) {                           // lanes 0/32 write node X
        float4 bb = *(const float4*)bias4;
        *(float4*)(u + nX * 4) =
            make_float4(pX0 + bb.x, pX1 + bb.y, pX2 + bb.z, pX3 + bb.w);
    }
    if (sl == 1) {                           // lanes 1/33 write node Y
        float4 bb = *(const float4*)bias4;
        *(float4*)(u + nY * 4) =
            make_float4(pY0 + bb.x, pY1 + bb.y, pY2 + bb.z, pY3 + bb.w);
    }
}

// Layer-2 aggregate on the rank-4 table (x8-padded rows, branch-free):
// pq[n,j] = norm*(w0*u[n,j] + w01*sum u[src,j]).  csr holds s*128 byte offsets;
// u row start (float index) = s*4 = offset>>5.
__global__ void agg_pq4_kernel(const float* __restrict__ u, const int* __restrict__ row_start,
                               const int* __restrict__ row_pdeg,
                               const int* __restrict__ csr_src,
                               const float* __restrict__ norm,
                               const float* __restrict__ wpan, float* __restrict__ pq,
                               int n_nodes) {
    int t = threadIdx.x;
    int node = blockIdx.x * 64 + (t >> 2);
    int j = t & 3;
    if (node >= n_nodes) return;
    int e0 = row_start[node];
    int pd = row_pdeg[node];
    float acc = 0.0f;
    for (int e = 0; e < pd; e += 8) {
#pragma unroll
        for (int k = 0; k < 8; k++) {
            int so = csr_src[e0 + e + k];
            acc += u[(so >> 5) + j];
        }
    }
    float w0 = wpan[0];
    float w01 = wpan[0] * wpan[1];
    pq[node * 4 + j] = norm[node] * (w0 * u[node * 4 + j] + w01 * acc);
}

__global__ void edge_out_kernel(const int* __restrict__ src, const int* __restrict__ dst,
                                const float* __restrict__ pq, const float* __restrict__ bc,
                                float* __restrict__ out, int n_edges) {
    int e = blockIdx.x * blockDim.x + threadIdx.x;
    if (e >= n_edges) return;
    int r = src[e], c = dst[e];
    float2 p = *(const float2*)(pq + r * 4);
    float2 q = *(const float2*)(pq + c * 4 + 2);
    float2 o = make_float2(p.x + q.x + bc[0], p.y + q.y + bc[1]);
    *(float2*)(out + e * 2) = o;
}

extern "C" void kernel_launch(void* const* d_in, const int* in_sizes, int n_in,
                              void* d_out, int out_size, void* d_ws, size_t ws_size,
                              hipStream_t stream) {
    const float* x      = (const float*)d_in[0];
    const int*   eidx   = (const int*)d_in[1];
    const float* w1_lin = (const float*)d_in[2];
    const float* b1_lin = (const float*)d_in[3];
    const float* w1_pan = (const float*)d_in[4];
    const float* w2_lin = (const float*)d_in[5];
    const float* b2_lin = (const float*)d_in[6];
    const float* w2_pan = (const float*)d_in[7];
    const float* wc     = (const float*)d_in[8];
    const float* bc     = (const float*)d_in[9];
    float* out = (float*)d_out;

    const int* src = eidx;           // edge_index[0]
    const int* dst = eidx + NEDGES;  // edge_index[1]

    // ---- workspace carve-up (all 256B-aligned) ----
    char* ws = (char*)d_ws;
    size_t off = 0;
    auto carve = [&](size_t bytes) {
        char* p = ws + off;
        off = (off + bytes + 255) & ~(size_t)255;
        return p;
    };
    int*   bucket_fill = (int*)carve((size_t)NB * 4);
    int*   row_start = (int*)carve((size_t)NNODES * 4);
    int*   row_pdeg  = (int*)carve((size_t)NNODES * 4);
    unsigned int* staging = (unsigned int*)carve((size_t)NB * CAP * 4);   // 12.8 MB
    int*   csr_src  = (int*)carve(((size_t)NB * CAPE + 256) * 4);         // 12.8 MB + slack
    float* nrm      = (float*)carve((size_t)NNODES * 4);
    unsigned short* bufA = (unsigned short*)carve((size_t)(NNODES + 1) * HIDC * 2);
    float* u        = (float*)carve((size_t)(NNODES + 1) * 4 * 4);
    float* pq       = (float*)carve((size_t)NNODES * 4 * 4);
    float* w44      = (float*)carve((size_t)64 * 4 * 4);
    float* bias4    = (float*)carve((size_t)4 * 4);
    unsigned short* wTh = (unsigned short*)carve((size_t)HIDC * INC * 2); // 16 KB
    unsigned short* wTl = (unsigned short*)carve((size_t)HIDC * INC * 2); // 16 KB
    (void)ws_size; (void)in_sizes; (void)n_in; (void)out_size;

    hipMemsetAsync(bucket_fill, 0, (size_t)NB * 4, stream);

    // prep: wT bf16 hi/lo split + w44/bias4 fold + bufA sentinel row
    prep_w_kernel<<<32, 256, 0, stream>>>(w1_lin, wTh, wTl, w2_lin, b2_lin, wc,
                                          w44, bias4, bufA);

    // fat kernel: edge binning (first 391 blocks) || layer-1 MFMA GEMM (hybrid staging)
    fat_kernel<<<NBLK_FILL + NBLK_LIN, 256, 0, stream>>>(
        x, wTh, wTl, b1_lin, bufA, src, dst, bucket_fill, staging);

    // CSR build pass 2: x8-padded rows + row_start/pdeg + dedup + norm + scatter
    fill2_kernel<<<NB, 256, 0, stream>>>(bucket_fill, staging, csr_src, row_start, row_pdeg,
                                         nrm, NNODES);

    // layer 1 aggregate+relu fused with rank-4 projection -> u (4 nodes/wave)
    agg_h_kernel<<<(NNODES / 16), 256, 0, stream>>>(
        (const unsigned int*)bufA, row_start, row_pdeg, csr_src, nrm, w1_pan, w44, bias4,
        u, NNODES);

    // layer 2 aggregate on the rank-4 table
    agg_pq4_kernel<<<(NNODES + 63) / 64, 256, 0, stream>>>(
        u, row_start, row_pdeg, csr_src, nrm, w2_pan, pq, NNODES);

    // edge head: out[e] = p[src[e]] + q[dst[e]] + bc
    edge_out_kernel<<<NEDGES / 256, 256, 0, stream>>>(src, dst, pq, bc, out, NEDGES);
}